// Round 9
// baseline (219.406 us; speedup 1.0000x reference)
//
#include <hip/hip_runtime.h>

typedef unsigned short u16;
typedef unsigned int   u32;
typedef __attribute__((ext_vector_type(8))) short short8;
typedef __attribute__((ext_vector_type(4))) float f32x4;
typedef __attribute__((ext_vector_type(16))) float f32x16;
typedef __attribute__((ext_vector_type(2))) unsigned int u32x2;

#define AS1 __attribute__((address_space(1)))
#define AS3 __attribute__((address_space(3)))

#define NSEQ  1025
#define BB    8
#define DD    768
#define HH    12
#define MROWS 8200   // B*N valid rows
#define MPAD  8320   // padded to 65*128
#define KPAD  1088   // keys padded to 17*64

__device__ __forceinline__ void gl2lds16(const void* g, void* l) {
  __builtin_amdgcn_global_load_lds((const AS1 u32*)g, (AS3 u32*)l, 16, 0, 0);
}
__device__ __forceinline__ u16 f2bf(float f) {
  u32 u = __float_as_uint(f);
  return (u16)((u + 0x7FFFu + ((u >> 16) & 1u)) >> 16);
}
__device__ __forceinline__ float bf2f(u16 u) { return __uint_as_float(((u32)u) << 16); }

// permlane32_swap: exchanges d0's high 32 lanes with d1's low 32 lanes.
__device__ __forceinline__ u32x2 pl32swap(u32 x, u32 y) {
#if __has_builtin(__builtin_amdgcn_permlane32_swap)
  return __builtin_amdgcn_permlane32_swap(x, y, false, false);
#else
  asm volatile("v_permlane32_swap_b32 %0, %1" : "+v"(x), "+v"(y));
  u32x2 r; r.x = x; r.y = y; return r;
#endif
}

// ---------------------------------------------------------------------------
// prep: cast x -> xb bf16 [MPAD x 768] (transposed (n,b)->(b,n), pad rows = 0),
//       w_qkv rows [768,2304) -> wkv bf16 [1536 x 768],
//       w_proj -> wpj bf16 [768 x 768]
// ---------------------------------------------------------------------------
__global__ __launch_bounds__(256) void prep(const float* __restrict__ x,
                                            const float* __restrict__ wqkv,
                                            const float* __restrict__ wproj,
                                            u16* __restrict__ xb,
                                            u16* __restrict__ wkv,
                                            u16* __restrict__ wpj) {
  const int XB_G  = MPAD * 192;   // float4 groups
  const int WKV_G = 1536 * 192;
  const int WPJ_G = 768 * 192;
  int g = blockIdx.x * 256 + threadIdx.x;
  float4 v;
  u16* dst;
  size_t di;
  if (g < XB_G) {
    int m = g / 192, e4 = g - m * 192;
    if (m < MROWS) {
      int bb = m / NSEQ, ns = m - bb * NSEQ;
      v = ((const float4*)x)[(size_t)(ns * BB + bb) * 192 + e4];
    } else {
      v.x = v.y = v.z = v.w = 0.f;
    }
    dst = xb; di = (size_t)g;
  } else if (g < XB_G + WKV_G) {
    int r = g - XB_G;
    v = ((const float4*)wqkv)[(size_t)147456 + r];  // skip first 768 rows
    dst = wkv; di = (size_t)r;
  } else if (g < XB_G + WKV_G + WPJ_G) {
    int r = g - XB_G - WKV_G;
    v = ((const float4*)wproj)[r];
    dst = wpj; di = (size_t)r;
  } else {
    return;
  }
  uint2 o;
  o.x = (u32)f2bf(v.x) | ((u32)f2bf(v.y) << 16);
  o.y = (u32)f2bf(v.z) | ((u32)f2bf(v.w) << 16);
  ((uint2*)dst)[di] = o;
}

// ---------------------------------------------------------------------------
// gemm_bt: C[m,n] = sum_k A[m,k]*W[n,k]; 128x128 tile, BK=64.
// v9: T3 MINIMUM 2-PHASE — double-buffered LDS, ONE barrier/kt, stage(kt+1)
// issued BEFORE compute(kt): the barrier's vmcnt(0) drains loads that had a
// full compute phase to land (old 1-phase structure exposed the entire load
// latency every kt). LDS 64KB -> 2 blocks/CU (occupancy risk accepted as the
// experiment; m132 caveat). XCD-aware 1D grid. MODE 0 (qkv GEMM): bf16 store.
// ---------------------------------------------------------------------------
template <int MODE, int NT>
__global__ __launch_bounds__(256) void gemm_bt(const u16* __restrict__ A,
                                               const u16* __restrict__ W,
                                               u16* __restrict__ Cbf,
                                               float* __restrict__ Cf,
                                               const float* __restrict__ bias,
                                               int ldc) {
  __shared__ u16 sA[2][8192];  // 2 x 16KB
  __shared__ u16 sW[2][8192];  // 2 x 16KB
  const int id = blockIdx.x;
  const int rx = id & 7, qx = id >> 3;
  const int kq = qx / NT;
  const int m_t = rx + (kq << 3);
  if (m_t > 64) return;
  const int n_t = qx - kq * NT;
  const int m0 = m_t << 7, n0 = n_t << 7;

  const int tid = threadIdx.x;
  const int w = tid >> 6, lane = tid & 63;
  const int wm = w & 1, wn = w >> 1;
  const int lc = lane & 15, lr = lane >> 4;

  f32x4 zero4 = {0.f, 0.f, 0.f, 0.f};
  f32x4 acc[4][4];
#pragma unroll
  for (int i = 0; i < 4; ++i)
#pragma unroll
    for (int j = 0; j < 4; ++j) acc[i][j] = zero4;

  const int r0 = tid >> 3;        // staging row 0..31 (+32 per chunk j)
  const int ko = (tid & 7) << 3;  // k-offset in elements
  const u16* gA = A + (size_t)(m0 + r0) * DD + ko;
  const u16* gW = W + (size_t)(n0 + r0) * DD + ko;
  const int soff = tid * 16;      // byte offset within one buffer

  // prologue: stage kt=0 into buf 0
#pragma unroll
  for (int j = 0; j < 4; ++j) {
    gl2lds16(gA + (size_t)j * 32 * DD, (char*)sA[0] + soff + j * 4096);
    gl2lds16(gW + (size_t)j * 32 * DD, (char*)sW[0] + soff + j * 4096);
  }

#pragma unroll 1
  for (int kt = 0; kt < 12; ++kt) {
    const int cur = kt & 1;
    // one barrier: vmcnt(0) drains buf[cur] loads (issued a full compute
    // phase ago); compute(kt-1)'s reads of buf[cur^1] are pre-barrier.
    __syncthreads();
    if (kt < 11) {
#pragma unroll
      for (int j = 0; j < 4; ++j) {
        gl2lds16(gA + (size_t)j * 32 * DD + (kt + 1) * 64, (char*)sA[cur ^ 1] + soff + j * 4096);
        gl2lds16(gW + (size_t)j * 32 * DD + (kt + 1) * 64, (char*)sW[cur ^ 1] + soff + j * 4096);
      }
    }
    const char* bA = (const char*)sA[cur];
    const char* bW = (const char*)sW[cur];
#pragma unroll
    for (int kk = 0; kk < 2; ++kk) {
      short8 af[4], wf[4];
#pragma unroll
      for (int mt = 0; mt < 4; ++mt)
        af[mt] = *(const short8*)(bA + ((wm << 6) + (mt << 4) + lc) * 128 + (kk << 6) + (lr << 4));
#pragma unroll
      for (int nt = 0; nt < 4; ++nt)
        wf[nt] = *(const short8*)(bW + ((wn << 6) + (nt << 4) + lc) * 128 + (kk << 6) + (lr << 4));
#pragma unroll
      for (int mt = 0; mt < 4; ++mt)
#pragma unroll
        for (int nt = 0; nt < 4; ++nt)
          acc[mt][nt] = __builtin_amdgcn_mfma_f32_16x16x32_bf16(af[mt], wf[nt], acc[mt][nt], 0, 0, 0);
    }
  }

  if (MODE == 0) {
#pragma unroll
    for (int mt = 0; mt < 4; ++mt)
#pragma unroll
      for (int r = 0; r < 4; ++r) {
        int m = m0 + (wm << 6) + (mt << 4) + (lr << 2) + r;
        if (m < MROWS) {
          size_t base = (size_t)m * ldc + n0 + (wn << 6) + lc;
#pragma unroll
          for (int nt = 0; nt < 4; ++nt) Cbf[base + (nt << 4)] = f2bf(acc[mt][nt][r]);
        }
      }
  } else {
    float b4[4];
#pragma unroll
    for (int nt = 0; nt < 4; ++nt) b4[nt] = bias[n0 + (wn << 6) + (nt << 4) + lc];
#pragma unroll
    for (int mt = 0; mt < 4; ++mt)
#pragma unroll
      for (int r = 0; r < 4; ++r) {
        int m = m0 + (wm << 6) + (mt << 4) + (lr << 2) + r;
        if (m < MROWS) {
          int bb = m / NSEQ;
          int ns = m - bb * NSEQ;
          float* o = Cf + (size_t)ns * (BB * DD) + bb * DD + n0 + (wn << 6) + lc;
#pragma unroll
          for (int nt = 0; nt < 4; ++nt) o[nt << 4] = acc[mt][nt][r] + b4[nt];
        }
      }
  }
}

// ---------------------------------------------------------------------------
// gemm_proj: proj GEMM, 128x64 tiles (780 live blocks). v9: same T3 2-phase
// dbuf rotation (LDS 48KB -> 3 blocks/CU). Epilogue: +bias, fp32 scatter.
// ---------------------------------------------------------------------------
__global__ __launch_bounds__(256) void gemm_proj(const u16* __restrict__ A,
                                                 const u16* __restrict__ W,
                                                 float* __restrict__ Cf,
                                                 const float* __restrict__ bias) {
  __shared__ u16 sA[2][8192];  // 2 x 16KB
  __shared__ u16 sW[2][4096];  // 2 x 8KB
  const int id = blockIdx.x;
  const int rx = id & 7, qx = id >> 3;   // qx 0..107
  const int kq = qx / 12;                 // 0..8
  const int m_t = rx + (kq << 3);
  if (m_t > 64) return;
  const int n_t = qx - kq * 12;           // 0..11
  const int m0 = m_t << 7, n0 = n_t << 6;

  const int tid = threadIdx.x;
  const int w = tid >> 6, lane = tid & 63;
  const int lc = lane & 15, lr = lane >> 4;

  f32x4 zero4 = {0.f, 0.f, 0.f, 0.f};
  f32x4 acc[2][4];
#pragma unroll
  for (int i = 0; i < 2; ++i)
#pragma unroll
    for (int j = 0; j < 4; ++j) acc[i][j] = zero4;

  const int r0 = tid >> 3;        // staging row 0..31 (+32 per chunk j)
  const int ko = (tid & 7) << 3;  // k-offset in elements
  const u16* gA = A + (size_t)(m0 + r0) * DD + ko;
  const u16* gW = W + (size_t)(n0 + r0) * DD + ko;
  const int soff = tid * 16;

  // prologue: stage kt=0 into buf 0
#pragma unroll
  for (int j = 0; j < 4; ++j)
    gl2lds16(gA + (size_t)j * 32 * DD, (char*)sA[0] + soff + j * 4096);
#pragma unroll
  for (int j = 0; j < 2; ++j)
    gl2lds16(gW + (size_t)j * 32 * DD, (char*)sW[0] + soff + j * 4096);

#pragma unroll 1
  for (int kt = 0; kt < 12; ++kt) {
    const int cur = kt & 1;
    __syncthreads();
    if (kt < 11) {
#pragma unroll
      for (int j = 0; j < 4; ++j)
        gl2lds16(gA + (size_t)j * 32 * DD + (kt + 1) * 64, (char*)sA[cur ^ 1] + soff + j * 4096);
#pragma unroll
      for (int j = 0; j < 2; ++j)
        gl2lds16(gW + (size_t)j * 32 * DD + (kt + 1) * 64, (char*)sW[cur ^ 1] + soff + j * 4096);
    }
    const char* bA = (const char*)sA[cur];
    const char* bW = (const char*)sW[cur];
#pragma unroll
    for (int kk = 0; kk < 2; ++kk) {
      short8 af[2], wf[4];
#pragma unroll
      for (int mt = 0; mt < 2; ++mt)
        af[mt] = *(const short8*)(bA + ((w << 5) + (mt << 4) + lc) * 128 + (kk << 6) + (lr << 4));
#pragma unroll
      for (int nt = 0; nt < 4; ++nt)
        wf[nt] = *(const short8*)(bW + (((nt << 4) + lc) << 7) + (kk << 6) + (lr << 4));
#pragma unroll
      for (int mt = 0; mt < 2; ++mt)
#pragma unroll
        for (int nt = 0; nt < 4; ++nt)
          acc[mt][nt] = __builtin_amdgcn_mfma_f32_16x16x32_bf16(af[mt], wf[nt], acc[mt][nt], 0, 0, 0);
    }
  }

  float b4[4];
#pragma unroll
  for (int nt = 0; nt < 4; ++nt) b4[nt] = bias[n0 + (nt << 4) + lc];
#pragma unroll
  for (int mt = 0; mt < 2; ++mt)
#pragma unroll
    for (int r = 0; r < 4; ++r) {
      int m = m0 + (w << 5) + (mt << 4) + (lr << 2) + r;
      if (m < MROWS) {
        int bb = m / NSEQ;
        int ns = m - bb * NSEQ;
        float* o = Cf + (size_t)ns * (BB * DD) + bb * DD + n0 + lc;
#pragma unroll
        for (int nt = 0; nt < 4; ++nt) o[nt << 4] = acc[mt][nt][r] + b4[nt];
      }
    }
}

// ---------------------------------------------------------------------------
// q0: fp32 q row 0 per batch: q0[b,d'] = sum_e x[0,b,e]*w_qkv[d',e], d' in [0,768)
// ---------------------------------------------------------------------------
__global__ __launch_bounds__(256) void q0_kernel(const float* __restrict__ x,
                                                 const float* __restrict__ wq,
                                                 float* __restrict__ q0) {
  __shared__ float red[256];
  int bid = blockIdx.x;
  int b = bid / HH, c = bid - b * HH;
  int tid = threadIdx.x;
  int dp = (c << 6) + (tid >> 2), part = tid & 3;
  const float4* x4 = (const float4*)(x + (size_t)b * DD + part * 192);
  const float4* w4 = (const float4*)(wq + (size_t)dp * DD + part * 192);
  float acc = 0.f;
#pragma unroll 4
  for (int e = 0; e < 48; ++e) {
    float4 a = x4[e], w = w4[e];
    acc += a.x * w.x + a.y * w.y + a.z * w.z + a.w * w.w;
  }
  red[tid] = acc;
  __syncthreads();
  if (part == 0) q0[b * DD + dp] = red[tid] + red[tid + 1] + red[tid + 2] + red[tid + 3];
}

// ---------------------------------------------------------------------------
// transpose_v: vT[bh][d][key] raw (KPAD cols, zero-padded) AND
//              vn[bh][key][64] = v/max(||v||,eps) bf16 (zero pad rows)
// ---------------------------------------------------------------------------
__global__ __launch_bounds__(256) void transpose_v(const u16* __restrict__ kv,
                                                   u16* __restrict__ vT,
                                                   u16* __restrict__ vn) {
  __shared__ u16 tile[64][72];
  __shared__ float red[256];
  __shared__ float sInv[64];
  int bid = blockIdx.x;
  int kc = bid % 17;
  int t2 = bid / 17;
  int h = t2 % HH, b = t2 / HH;
  int tid = threadIdx.x;
  int kl = tid >> 2, dc = (tid & 3) << 4;
  int key = kc * 64 + kl;
  u32 vals[8];
  if (key < NSEQ) {
    const u32* g = (const u32*)(kv + ((size_t)b * NSEQ + key) * 1536 + DD + h * 64 + dc);
#pragma unroll
    for (int i = 0; i < 8; ++i) vals[i] = g[i];
  } else {
#pragma unroll
    for (int i = 0; i < 8; ++i) vals[i] = 0;
  }
  float part = 0.f;
#pragma unroll
  for (int i = 0; i < 8; ++i) {
    float a = bf2f((u16)(vals[i] & 0xFFFF));
    float c = bf2f((u16)(vals[i] >> 16));
    part += a * a + c * c;
    ((u32*)&tile[kl][dc])[i] = vals[i];
  }
  red[tid] = part;
  __syncthreads();
  if ((tid & 3) == 0) {
    float s = red[tid] + red[tid + 1] + red[tid + 2] + red[tid + 3];
    sInv[kl] = (key < NSEQ) ? 1.0f / fmaxf(sqrtf(s), 1e-6f) : 0.0f;
  }
  __syncthreads();
  // normalized bf16 rows -> vn
  float iv = sInv[kl];
  u32 ovn[8];
#pragma unroll
  for (int i = 0; i < 8; ++i) {
    float a = bf2f((u16)(vals[i] & 0xFFFF)) * iv;
    float c = bf2f((u16)(vals[i] >> 16)) * iv;
    ovn[i] = (u32)f2bf(a) | ((u32)f2bf(c) << 16);
  }
  u32* on = (u32*)(vn + ((size_t)(b * HH + h) * KPAD + key) * 64 + dc);
#pragma unroll
  for (int i = 0; i < 8; ++i) on[i] = ovn[i];
  // raw transpose -> vT
  int dl = tid >> 2, ks = (tid & 3) << 4;
  u32 ov[8];
#pragma unroll
  for (int i = 0; i < 8; ++i)
    ov[i] = (u32)tile[ks + 2 * i][dl] | ((u32)tile[ks + 2 * i + 1][dl] << 16);
  u16* o = vT + (size_t)(b * HH + h) * 64 * KPAD + (size_t)dl * KPAD + kc * 64 + ks;
#pragma unroll
  for (int i = 0; i < 8; ++i) ((u32*)o)[i] = ov[i];
}

// ---------------------------------------------------------------------------
// row0_part: grid (96,8). Chunk ck covers keys [ck*128, ck*128+128) (chunk 7
// also key 1024). UNNORMALIZED partials: num[d] = sum exp(s)*v[d], den = sum
// exp(s) -> part[bh][ck][65]; vv_attn (y==0) blocks finalize row 0.
// ---------------------------------------------------------------------------
__global__ __launch_bounds__(256) void row0_part(const float* __restrict__ q0,
                                                 const u16* __restrict__ kv,
                                                 float* __restrict__ part) {
  __shared__ float sq[64];
  __shared__ float sc[129];
  __shared__ float red[256];
  __shared__ float rpv[32][68];  // [key-part][dim], +4 pad breaks bank alias
  int bh = blockIdx.x, ck = blockIdx.y;
  int b = bh / HH, h = bh - b * HH;
  int tid = threadIdx.x;
  if (tid < 64) sq[tid] = q0[b * DD + h * 64 + tid];
  if (tid == 64) sc[128] = 0.f;
  __syncthreads();
  const int nk = (ck == 7) ? 129 : 128;  // chunk 7 also owns key 1024
  if (tid < nk) {
    int n = ck * 128 + tid;  // tid==128 -> n==1024
    const u32* kr = (const u32*)(kv + ((size_t)b * NSEQ + n) * 1536 + h * 64);
    float s = 0.f;
#pragma unroll
    for (int i = 0; i < 32; ++i) {
      u32 u = kr[i];
      s += bf2f((u16)(u & 0xFFFF)) * sq[2 * i] + bf2f((u16)(u >> 16)) * sq[2 * i + 1];
    }
    sc[tid] = __expf(s * 0.125f);
  }
  __syncthreads();
  // den partial
  float ds = (tid < nk) ? sc[tid] : 0.f;
  red[tid] = ds;
  __syncthreads();
  for (int st = 128; st > 0; st >>= 1) {
    if (tid < st) red[tid] += red[tid + st];
    __syncthreads();
  }
  // PV partial: thread (kp, dc) accumulates dims [dc,dc+8) over local keys kp+32j
  int kp = tid >> 3, dc = (tid & 7) << 3;
  const u16* vb = kv + (size_t)b * NSEQ * 1536 + DD + h * 64 + dc;
  float acc[8];
#pragma unroll
  for (int i = 0; i < 8; ++i) acc[i] = 0.f;
#pragma unroll
  for (int j = 0; j < 4; ++j) {
    int kl = kp + (j << 5);
    uint4 v = *(const uint4*)(vb + (size_t)(ck * 128 + kl) * 1536);
    float p = sc[kl];
    acc[0] += p * bf2f((u16)(v.x & 0xFFFF));
    acc[1] += p * bf2f((u16)(v.x >> 16));
    acc[2] += p * bf2f((u16)(v.y & 0xFFFF));
    acc[3] += p * bf2f((u16)(v.y >> 16));
    acc[4] += p * bf2f((u16)(v.z & 0xFFFF));
    acc[5] += p * bf2f((u16)(v.z >> 16));
    acc[6] += p * bf2f((u16)(v.w & 0xFFFF));
    acc[7] += p * bf2f((u16)(v.w >> 16));
  }
  if (ck == 7 && kp == 0) {  // key 1024
    uint4 v = *(const uint4*)(vb + (size_t)1024 * 1536);
    float p = sc[128];
    acc[0] += p * bf2f((u16)(v.x & 0xFFFF));
    acc[1] += p * bf2f((u16)(v.x >> 16));
    acc[2] += p * bf2f((u16)(v.y & 0xFFFF));
    acc[3] += p * bf2f((u16)(v.y >> 16));
    acc[4] += p * bf2f((u16)(v.z & 0xFFFF));
    acc[5] += p * bf2f((u16)(v.z >> 16));
    acc[6] += p * bf2f((u16)(v.w & 0xFFFF));
    acc[7] += p * bf2f((u16)(v.w >> 16));
  }
#pragma unroll
  for (int i = 0; i < 8; ++i) rpv[kp][dc + i] = acc[i];
  __syncthreads();
  float* po = part + ((size_t)bh * 8 + ck) * 65;
  if (tid < 64) {
    float s = 0.f;
#pragma unroll
    for (int p = 0; p < 32; ++p) s += rpv[p][tid];
    po[tid] = s;
  }
  if (tid == 64) po[64] = red[0];
}

// ---------------------------------------------------------------------------
// vv_attn (r8 structure, kept): 32x32x16 MFMA + in-register P via
// permlane32_swap; zero bank conflicts; LDS 16KB. Measured floor ~48us —
// six structural experiments (conflict-fix -5us; dbuf, 2x-occupancy,
// fence-merge, setprio, 32x32+in-reg-P all null) — left unchanged.
// ---------------------------------------------------------------------------
__global__ __launch_bounds__(256, 3) void vv_attn(const u16* __restrict__ vn,
                                                  const u16* __restrict__ vT,
                                                  u16* __restrict__ attn,
                                                  const float* __restrict__ part) {
  __shared__ u16 sK[4096];  // [ds(4)][mt(2)][lane][8]  8KB  (keys x dims, frag order)
  __shared__ u16 sV[4096];  // [ks(4)][nt(2)][lane][8]  8KB  (dims x keys, frag order)

  const int tid = threadIdx.x, w = tid >> 6, lane = tid & 63;
  const int l5 = lane >> 5;
  const int bh = blockIdx.x;        // 0..95
  const int m0 = blockIdx.y << 7;
  const int b = bh / HH, h = bh - b * HH;
  const char* nb = (const char*)(vn + (size_t)bh * KPAD * 64);  // 128B rows (key-major)
  const char* tb = (const char*)(vT + (size_t)bh * 64 * KPAD);  // 2176B rows (d-major)

  // Q B-frags (32x32x16): qreg[ds] = Q[1+m0+w*32+(lane&31)][16ds + l5*8 .. +8)
  short8 qreg[4];
#pragma unroll
  for (int ds = 0; ds < 4; ++ds)
    qreg[ds] = *(const short8*)(nb +
        (size_t)(1 + m0 + (w << 5) + (lane & 31)) * 128 + (ds << 5) + (l5 << 4));

  const char* srcK[2];
  const char* srcV[2];
  int offKV[2];
#pragma unroll
  for (int j = 0; j < 2; ++j) {
    srcK[j] = nb + (size_t)((j << 5) + (lane & 31)) * 128 + (w << 5) + (l5 << 4);
    srcV[j] = tb + (size_t)((j << 5) + (lane & 31)) * (KPAD * 2) + (w << 5) + (l5 << 4);
    offKV[j] = (w << 11) + (j << 10) + (lane << 4);
  }

  f32x16 oacc[2];
  f32x16 dacc;
#pragma unroll
  for (int i = 0; i < 16; ++i) { oacc[0][i] = 0.f; oacc[1][i] = 0.f; dacc[i] = 0.f; }
  short8 ones;
#pragma unroll
  for (int i = 0; i < 8; ++i) ones[i] = (short)0x3F80;  // bf16 1.0

  const float CEXP = 0.1803368801111204f;  // 0.125 * log2(e)

  const char* rdK = (const char*)sK + (lane << 4);
  const char* rdV = (const char*)sV + (lane << 4);

#pragma unroll 1
  for (int kt = 0; kt < 17; ++kt) {
    __syncthreads();  // protect sK/sV from previous iteration's readers
#pragma unroll
    for (int j = 0; j < 2; ++j) {
      gl2lds16(srcK[j] + (size_t)kt * 8192, (char*)sK + offKV[j]);
      gl2lds16(srcV[j] + (size_t)kt * 128,  (char*)sV + offKV[j]);
    }
    __syncthreads();  // vmcnt(0) drain + publish block-wide

    // S^T = Kn_tile @ Qn^T : 2 key-tiles x 4 d-steps
    f32x16 sacc[2];
#pragma unroll
    for (int i = 0; i < 16; ++i) { sacc[0][i] = 0.f; sacc[1][i] = 0.f; }
#pragma unroll
    for (int ds = 0; ds < 4; ++ds) {
      short8 ak0 = *(const short8*)(rdK + ((ds << 1) << 10));
      short8 ak1 = *(const short8*)(rdK + (((ds << 1) + 1) << 10));
      sacc[0] = __builtin_amdgcn_mfma_f32_32x32x16_bf16(ak0, qreg[ds], sacc[0], 0, 0, 0);
      sacc[1] = __builtin_amdgcn_mfma_f32_32x32x16_bf16(ak1, qreg[ds], sacc[1], 0, 0, 0);
    }

    // p = exp2(s*CEXP); pack pairs to bf16; permlane assembles A-frags;
    // PV + den accumulate. All in registers.
#pragma unroll
    for (int mt = 0; mt < 2; ++mt) {
      u32 pk[8];
#pragma unroll
      for (int i = 0; i < 8; ++i) {
        float e0 = __builtin_amdgcn_exp2f(sacc[mt][2 * i] * CEXP);
        float e1 = __builtin_amdgcn_exp2f(sacc[mt][2 * i + 1] * CEXP);
        if (kt == 16) {  // only global key 1024 (mt==0, reg==0, lane<32) valid
          e0 = (mt == 0 && i == 0 && l5 == 0) ? e0 : 0.f;
          e1 = 0.f;
        }
        pk[i] = __builtin_amdgcn_perm(__float_as_uint(e1) + 0x8000u,
                                      __float_as_uint(e0) + 0x8000u, 0x07060302u);
      }
#pragma unroll
      for (int s = 0; s < 2; ++s) {
        u32x2 r0 = pl32swap(pk[4 * s], pk[4 * s + 2]);
        u32x2 r1 = pl32swap(pk[4 * s + 1], pk[4 * s + 3]);
        u32 paw[4] = {r0.x, r1.x, r0.y, r1.y};  // A elems (0,1)(2,3)(4,5)(6,7)
        short8 pa;
#pragma unroll
        for (int q2 = 0; q2 < 4; ++q2) {
          pa[2 * q2]     = (short)(paw[q2] & 0xFFFFu);
          pa[2 * q2 + 1] = (short)(paw[q2] >> 16);
        }
        int ksg = (mt << 1) + s;  // global 16-key step
        short8 bv0 = *(const short8*)(rdV + ((ksg << 1) << 10));
        short8 bv1 = *(const short8*)(rdV + (((ksg << 1) + 1) << 10));
        oacc[0] = __builtin_amdgcn_mfma_f32_32x32x16_bf16(pa, bv0, oacc[0], 0, 0, 0);
        oacc[1] = __builtin_amdgcn_mfma_f32_32x32x16_bf16(pa, bv1, oacc[1], 0, 0, 0);
        dacc    = __builtin_amdgcn_mfma_f32_32x32x16_bf16(pa, ones, dacc, 0, 0, 0);
      }
    }
  }

  // epilogue: lane holds d = 32nt + (lane&31), q = (reg&3)+8*(reg>>2)+4*l5
#pragma unroll
  for (int reg = 0; reg < 16; ++reg) {
    int q = (reg & 3) + ((reg >> 2) << 3) + (l5 << 2);
    int nseq = 1 + m0 + (w << 5) + q;
    float rdn = 1.0f / dacc[reg];
    u16* o = attn + ((size_t)b * NSEQ + nseq) * DD + h * 64 + (lane & 31);
    o[0]  = f2bf(oacc[0][reg] * rdn);
    o[32] = f2bf(oacc[1][reg] * rdn);
  }

  // finalize attention row 0 from row0_part partials (y==0 blocks only)
  if (blockIdx.y == 0 && tid < 64) {
    const float* pp = part + (size_t)bh * 8 * 65;
    float num = 0.f, den = 0.f;
#pragma unroll
    for (int c = 0; c < 8; ++c) {
      num += pp[c * 65 + tid];
      den += pp[c * 65 + 64];
    }
    attn[(size_t)b * NSEQ * DD + h * 64 + tid] = f2bf(num / den);
  }
}

// ---------------------------------------------------------------------------
// launcher
// ---------------------------------------------------------------------------
extern "C" void kernel_launch(void* const* d_in, const int* in_sizes, int n_in,
                              void* d_out, int out_size, void* d_ws, size_t ws_size,
                              hipStream_t stream) {
  const float* x      = (const float*)d_in[0];
  const float* w_qkv  = (const float*)d_in[1];
  const float* w_proj = (const float*)d_in[2];
  const float* b_proj = (const float*)d_in[3];
  float* out = (float*)d_out;
  char* ws = (char*)d_ws;

  // workspace layout (bytes). xb region is reused by vT after the qkv GEMM;
  // wkv region (dead after gemm<0>) is reused by the row-0 partials.
  u16*   xb   = (u16*)(ws + 0);            // 8320*768*2   = 12,779,520
  u16*   vT   = (u16*)(ws + 0);            // 96*64*1088*2 = 13,369,344 (reuses xb)
  u16*   wkv  = (u16*)(ws + 13369344);     // 1536*768*2   =  2,359,296
  float* r0p  = (float*)(ws + 13369344);   // 96*8*65*4    =    199,680 (reuses wkv)
  u16*   wpj  = (u16*)(ws + 15728640);     // 768*768*2    =  1,179,648
  u16*   kvb  = (u16*)(ws + 16908288);     // 8320*1536*2  = 25,559,040
  float* q0   = (float*)(ws + 42467328);   // 8*768*4      =     24,576
  u16*   attn = (u16*)(ws + 42491904);     // 8320*768*2   = 12,779,520
  u16*   vn   = (u16*)(ws + 55271424);     // 96*1088*64*2 = 13,369,344
  // total: 68,640,768 bytes

  prep<<<7968, 256, 0, stream>>>(x, w_qkv, w_proj, xb, wkv, wpj);
  gemm_bt<0, 12><<<864, 256, 0, stream>>>(xb, wkv, kvb, nullptr, nullptr, 1536);
  q0_kernel<<<96, 256, 0, stream>>>(x, w_qkv, q0);
  transpose_v<<<1632, 256, 0, stream>>>(kvb, vT, vn);     // overwrites xb region
  row0_part<<<dim3(96, 8), 256, 0, stream>>>(q0, kvb, r0p);
  vv_attn<<<dim3(96, 8), 256, 0, stream>>>(vn, vT, attn, r0p);
  gemm_proj<<<864, 256, 0, stream>>>(attn, wpj, out, b_proj);
}

// Round 10
// 212.716 us; speedup vs baseline: 1.0314x; 1.0314x over previous
//
#include <hip/hip_runtime.h>

typedef unsigned short u16;
typedef unsigned int   u32;
typedef __attribute__((ext_vector_type(8))) short short8;
typedef __attribute__((ext_vector_type(4))) float f32x4;
typedef __attribute__((ext_vector_type(16))) float f32x16;
typedef __attribute__((ext_vector_type(2))) unsigned int u32x2;

#define AS1 __attribute__((address_space(1)))
#define AS3 __attribute__((address_space(3)))

#define NSEQ  1025
#define BB    8
#define DD    768
#define HH    12
#define MROWS 8200   // B*N valid rows
#define MPAD  8320   // padded to 65*128
#define KPAD  1088   // keys padded to 17*64

__device__ __forceinline__ void gl2lds16(const void* g, void* l) {
  __builtin_amdgcn_global_load_lds((const AS1 u32*)g, (AS3 u32*)l, 16, 0, 0);
}
__device__ __forceinline__ u16 f2bf(float f) {
  u32 u = __float_as_uint(f);
  return (u16)((u + 0x7FFFu + ((u >> 16) & 1u)) >> 16);
}
__device__ __forceinline__ float bf2f(u16 u) { return __uint_as_float(((u32)u) << 16); }

// permlane32_swap: exchanges d0's high 32 lanes with d1's low 32 lanes.
__device__ __forceinline__ u32x2 pl32swap(u32 x, u32 y) {
#if __has_builtin(__builtin_amdgcn_permlane32_swap)
  return __builtin_amdgcn_permlane32_swap(x, y, false, false);
#else
  asm volatile("v_permlane32_swap_b32 %0, %1" : "+v"(x), "+v"(y));
  u32x2 r; r.x = x; r.y = y; return r;
#endif
}

// ---------------------------------------------------------------------------
// prep: cast x -> xb bf16 [MPAD x 768] (transposed (n,b)->(b,n), pad rows = 0),
//       w_qkv rows [768,2304) -> wkv bf16 [1536 x 768],
//       w_proj -> wpj bf16 [768 x 768]
// ---------------------------------------------------------------------------
__global__ __launch_bounds__(256) void prep(const float* __restrict__ x,
                                            const float* __restrict__ wqkv,
                                            const float* __restrict__ wproj,
                                            u16* __restrict__ xb,
                                            u16* __restrict__ wkv,
                                            u16* __restrict__ wpj) {
  const int XB_G  = MPAD * 192;   // float4 groups
  const int WKV_G = 1536 * 192;
  const int WPJ_G = 768 * 192;
  int g = blockIdx.x * 256 + threadIdx.x;
  float4 v;
  u16* dst;
  size_t di;
  if (g < XB_G) {
    int m = g / 192, e4 = g - m * 192;
    if (m < MROWS) {
      int bb = m / NSEQ, ns = m - bb * NSEQ;
      v = ((const float4*)x)[(size_t)(ns * BB + bb) * 192 + e4];
    } else {
      v.x = v.y = v.z = v.w = 0.f;
    }
    dst = xb; di = (size_t)g;
  } else if (g < XB_G + WKV_G) {
    int r = g - XB_G;
    v = ((const float4*)wqkv)[(size_t)147456 + r];  // skip first 768 rows
    dst = wkv; di = (size_t)r;
  } else if (g < XB_G + WKV_G + WPJ_G) {
    int r = g - XB_G - WKV_G;
    v = ((const float4*)wproj)[r];
    dst = wpj; di = (size_t)r;
  } else {
    return;
  }
  uint2 o;
  o.x = (u32)f2bf(v.x) | ((u32)f2bf(v.y) << 16);
  o.y = (u32)f2bf(v.z) | ((u32)f2bf(v.w) << 16);
  ((uint2*)dst)[di] = o;
}

// ---------------------------------------------------------------------------
// gemm_bt: C[m,n] = sum_k A[m,k]*W[n,k]; 128x128 tile, BK=64. XCD-aware 1D
// grid. NT = n-tiles. MODE 0 (qkv GEMM): bf16 store. Single-buffer 1-phase:
// measured best (r9's 2-phase dbuf at 64KB LDS -> 2 blocks/CU regressed
// +5.6us; m132 occupancy cliff — TLP beats source-level pipelining here).
// ---------------------------------------------------------------------------
template <int MODE, int NT>
__global__ __launch_bounds__(256) void gemm_bt(const u16* __restrict__ A,
                                               const u16* __restrict__ W,
                                               u16* __restrict__ Cbf,
                                               float* __restrict__ Cf,
                                               const float* __restrict__ bias,
                                               int ldc) {
  __shared__ u16 sA[128 * 64];
  __shared__ u16 sW[128 * 64];
  const int id = blockIdx.x;
  const int rx = id & 7, qx = id >> 3;
  const int kq = qx / NT;
  const int m_t = rx + (kq << 3);
  if (m_t > 64) return;
  const int n_t = qx - kq * NT;
  const int m0 = m_t << 7, n0 = n_t << 7;

  const int tid = threadIdx.x;
  const int w = tid >> 6, lane = tid & 63;
  const int wm = w & 1, wn = w >> 1;
  const int lc = lane & 15, lr = lane >> 4;

  f32x4 zero4 = {0.f, 0.f, 0.f, 0.f};
  f32x4 acc[4][4];
#pragma unroll
  for (int i = 0; i < 4; ++i)
#pragma unroll
    for (int j = 0; j < 4; ++j) acc[i][j] = zero4;

  const int r0 = tid >> 3;        // staging row 0..31 (+32 per chunk j)
  const int ko = (tid & 7) << 3;  // k-offset in elements
  const u16* gA = A + (size_t)(m0 + r0) * DD + ko;
  const u16* gW = W + (size_t)(n0 + r0) * DD + ko;
  char* lA = (char*)sA + tid * 16;
  char* lW = (char*)sW + tid * 16;

#pragma unroll 1
  for (int kt = 0; kt < 12; ++kt) {
    __syncthreads();
#pragma unroll
    for (int j = 0; j < 4; ++j) {
      gl2lds16(gA + (size_t)j * 32 * DD + kt * 64, lA + j * 4096);
      gl2lds16(gW + (size_t)j * 32 * DD + kt * 64, lW + j * 4096);
    }
    __syncthreads();
#pragma unroll
    for (int kk = 0; kk < 2; ++kk) {
      short8 af[4], wf[4];
#pragma unroll
      for (int mt = 0; mt < 4; ++mt)
        af[mt] = *(const short8*)((char*)sA + ((wm << 6) + (mt << 4) + lc) * 128 + (kk << 6) + (lr << 4));
#pragma unroll
      for (int nt = 0; nt < 4; ++nt)
        wf[nt] = *(const short8*)((char*)sW + ((wn << 6) + (nt << 4) + lc) * 128 + (kk << 6) + (lr << 4));
#pragma unroll
      for (int mt = 0; mt < 4; ++mt)
#pragma unroll
        for (int nt = 0; nt < 4; ++nt)
          acc[mt][nt] = __builtin_amdgcn_mfma_f32_16x16x32_bf16(af[mt], wf[nt], acc[mt][nt], 0, 0, 0);
    }
  }

  if (MODE == 0) {
#pragma unroll
    for (int mt = 0; mt < 4; ++mt)
#pragma unroll
      for (int r = 0; r < 4; ++r) {
        int m = m0 + (wm << 6) + (mt << 4) + (lr << 2) + r;
        if (m < MROWS) {
          size_t base = (size_t)m * ldc + n0 + (wn << 6) + lc;
#pragma unroll
          for (int nt = 0; nt < 4; ++nt) Cbf[base + (nt << 4)] = f2bf(acc[mt][nt][r]);
        }
      }
  } else {
    float b4[4];
#pragma unroll
    for (int nt = 0; nt < 4; ++nt) b4[nt] = bias[n0 + (wn << 6) + (nt << 4) + lc];
#pragma unroll
    for (int mt = 0; mt < 4; ++mt)
#pragma unroll
      for (int r = 0; r < 4; ++r) {
        int m = m0 + (wm << 6) + (mt << 4) + (lr << 2) + r;
        if (m < MROWS) {
          int bb = m / NSEQ;
          int ns = m - bb * NSEQ;
          float* o = Cf + (size_t)ns * (BB * DD) + bb * DD + n0 + (wn << 6) + lc;
#pragma unroll
          for (int nt = 0; nt < 4; ++nt) o[nt << 4] = acc[mt][nt][r] + b4[nt];
        }
      }
  }
}

// ---------------------------------------------------------------------------
// gemm_proj: proj GEMM with 128x64 tiles -> 780 live blocks; LDS 24KB.
// Epilogue: +bias, fp32 scatter to [N,B,D].
// ---------------------------------------------------------------------------
__global__ __launch_bounds__(256) void gemm_proj(const u16* __restrict__ A,
                                                 const u16* __restrict__ W,
                                                 float* __restrict__ Cf,
                                                 const float* __restrict__ bias) {
  __shared__ u16 sA[128 * 64];
  __shared__ u16 sW[64 * 64];
  const int id = blockIdx.x;
  const int rx = id & 7, qx = id >> 3;   // qx 0..107
  const int kq = qx / 12;                 // 0..8
  const int m_t = rx + (kq << 3);
  if (m_t > 64) return;
  const int n_t = qx - kq * 12;           // 0..11
  const int m0 = m_t << 7, n0 = n_t << 6;

  const int tid = threadIdx.x;
  const int w = tid >> 6, lane = tid & 63;
  const int lc = lane & 15, lr = lane >> 4;

  f32x4 zero4 = {0.f, 0.f, 0.f, 0.f};
  f32x4 acc[2][4];
#pragma unroll
  for (int i = 0; i < 2; ++i)
#pragma unroll
    for (int j = 0; j < 4; ++j) acc[i][j] = zero4;

  const int r0 = tid >> 3;        // staging row 0..31 (+32 per chunk j)
  const int ko = (tid & 7) << 3;  // k-offset in elements
  const u16* gA = A + (size_t)(m0 + r0) * DD + ko;
  const u16* gW = W + (size_t)(n0 + r0) * DD + ko;
  char* lA = (char*)sA + tid * 16;
  char* lW = (char*)sW + tid * 16;

#pragma unroll 1
  for (int kt = 0; kt < 12; ++kt) {
    __syncthreads();
#pragma unroll
    for (int j = 0; j < 4; ++j)
      gl2lds16(gA + (size_t)j * 32 * DD + kt * 64, lA + j * 4096);
#pragma unroll
    for (int j = 0; j < 2; ++j)
      gl2lds16(gW + (size_t)j * 32 * DD + kt * 64, lW + j * 4096);
    __syncthreads();
#pragma unroll
    for (int kk = 0; kk < 2; ++kk) {
      short8 af[2], wf[4];
#pragma unroll
      for (int mt = 0; mt < 2; ++mt)
        af[mt] = *(const short8*)((char*)sA + ((w << 5) + (mt << 4) + lc) * 128 + (kk << 6) + (lr << 4));
#pragma unroll
      for (int nt = 0; nt < 4; ++nt)
        wf[nt] = *(const short8*)((char*)sW + (((nt << 4) + lc) << 7) + (kk << 6) + (lr << 4));
#pragma unroll
      for (int mt = 0; mt < 2; ++mt)
#pragma unroll
        for (int nt = 0; nt < 4; ++nt)
          acc[mt][nt] = __builtin_amdgcn_mfma_f32_16x16x32_bf16(af[mt], wf[nt], acc[mt][nt], 0, 0, 0);
    }
  }

  float b4[4];
#pragma unroll
  for (int nt = 0; nt < 4; ++nt) b4[nt] = bias[n0 + (nt << 4) + lc];
#pragma unroll
  for (int mt = 0; mt < 2; ++mt)
#pragma unroll
    for (int r = 0; r < 4; ++r) {
      int m = m0 + (w << 5) + (mt << 4) + (lr << 2) + r;
      if (m < MROWS) {
        int bb = m / NSEQ;
        int ns = m - bb * NSEQ;
        float* o = Cf + (size_t)ns * (BB * DD) + bb * DD + n0 + lc;
#pragma unroll
        for (int nt = 0; nt < 4; ++nt) o[nt << 4] = acc[mt][nt][r] + b4[nt];
      }
    }
}

// ---------------------------------------------------------------------------
// q0: fp32 q row 0 per batch: q0[b,d'] = sum_e x[0,b,e]*w_qkv[d',e], d' in [0,768)
// ---------------------------------------------------------------------------
__global__ __launch_bounds__(256) void q0_kernel(const float* __restrict__ x,
                                                 const float* __restrict__ wq,
                                                 float* __restrict__ q0) {
  __shared__ float red[256];
  int bid = blockIdx.x;
  int b = bid / HH, c = bid - b * HH;
  int tid = threadIdx.x;
  int dp = (c << 6) + (tid >> 2), part = tid & 3;
  const float4* x4 = (const float4*)(x + (size_t)b * DD + part * 192);
  const float4* w4 = (const float4*)(wq + (size_t)dp * DD + part * 192);
  float acc = 0.f;
#pragma unroll 4
  for (int e = 0; e < 48; ++e) {
    float4 a = x4[e], w = w4[e];
    acc += a.x * w.x + a.y * w.y + a.z * w.z + a.w * w.w;
  }
  red[tid] = acc;
  __syncthreads();
  if (part == 0) q0[b * DD + dp] = red[tid] + red[tid + 1] + red[tid + 2] + red[tid + 3];
}

// ---------------------------------------------------------------------------
// transpose_v: vT[bh][d][key] raw (KPAD cols, zero-padded) AND
//              vn[bh][key][64] = v/max(||v||,eps) bf16 (zero pad rows)
// ---------------------------------------------------------------------------
__global__ __launch_bounds__(256) void transpose_v(const u16* __restrict__ kv,
                                                   u16* __restrict__ vT,
                                                   u16* __restrict__ vn) {
  __shared__ u16 tile[64][72];
  __shared__ float red[256];
  __shared__ float sInv[64];
  int bid = blockIdx.x;
  int kc = bid % 17;
  int t2 = bid / 17;
  int h = t2 % HH, b = t2 / HH;
  int tid = threadIdx.x;
  int kl = tid >> 2, dc = (tid & 3) << 4;
  int key = kc * 64 + kl;
  u32 vals[8];
  if (key < NSEQ) {
    const u32* g = (const u32*)(kv + ((size_t)b * NSEQ + key) * 1536 + DD + h * 64 + dc);
#pragma unroll
    for (int i = 0; i < 8; ++i) vals[i] = g[i];
  } else {
#pragma unroll
    for (int i = 0; i < 8; ++i) vals[i] = 0;
  }
  float part = 0.f;
#pragma unroll
  for (int i = 0; i < 8; ++i) {
    float a = bf2f((u16)(vals[i] & 0xFFFF));
    float c = bf2f((u16)(vals[i] >> 16));
    part += a * a + c * c;
    ((u32*)&tile[kl][dc])[i] = vals[i];
  }
  red[tid] = part;
  __syncthreads();
  if ((tid & 3) == 0) {
    float s = red[tid] + red[tid + 1] + red[tid + 2] + red[tid + 3];
    sInv[kl] = (key < NSEQ) ? 1.0f / fmaxf(sqrtf(s), 1e-6f) : 0.0f;
  }
  __syncthreads();
  // normalized bf16 rows -> vn
  float iv = sInv[kl];
  u32 ovn[8];
#pragma unroll
  for (int i = 0; i < 8; ++i) {
    float a = bf2f((u16)(vals[i] & 0xFFFF)) * iv;
    float c = bf2f((u16)(vals[i] >> 16)) * iv;
    ovn[i] = (u32)f2bf(a) | ((u32)f2bf(c) << 16);
  }
  u32* on = (u32*)(vn + ((size_t)(b * HH + h) * KPAD + key) * 64 + dc);
#pragma unroll
  for (int i = 0; i < 8; ++i) on[i] = ovn[i];
  // raw transpose -> vT
  int dl = tid >> 2, ks = (tid & 3) << 4;
  u32 ov[8];
#pragma unroll
  for (int i = 0; i < 8; ++i)
    ov[i] = (u32)tile[ks + 2 * i][dl] | ((u32)tile[ks + 2 * i + 1][dl] << 16);
  u16* o = vT + (size_t)(b * HH + h) * 64 * KPAD + (size_t)dl * KPAD + kc * 64 + ks;
#pragma unroll
  for (int i = 0; i < 8; ++i) ((u32*)o)[i] = ov[i];
}

// ---------------------------------------------------------------------------
// row0_part: grid (96,8). Chunk ck covers keys [ck*128, ck*128+128) (chunk 7
// also key 1024). UNNORMALIZED partials: num[d] = sum exp(s)*v[d], den = sum
// exp(s) -> part[bh][ck][65]; vv_attn (y==0) blocks finalize row 0.
// ---------------------------------------------------------------------------
__global__ __launch_bounds__(256) void row0_part(const float* __restrict__ q0,
                                                 const u16* __restrict__ kv,
                                                 float* __restrict__ part) {
  __shared__ float sq[64];
  __shared__ float sc[129];
  __shared__ float red[256];
  __shared__ float rpv[32][68];  // [key-part][dim], +4 pad breaks bank alias
  int bh = blockIdx.x, ck = blockIdx.y;
  int b = bh / HH, h = bh - b * HH;
  int tid = threadIdx.x;
  if (tid < 64) sq[tid] = q0[b * DD + h * 64 + tid];
  if (tid == 64) sc[128] = 0.f;
  __syncthreads();
  const int nk = (ck == 7) ? 129 : 128;  // chunk 7 also owns key 1024
  if (tid < nk) {
    int n = ck * 128 + tid;  // tid==128 -> n==1024
    const u32* kr = (const u32*)(kv + ((size_t)b * NSEQ + n) * 1536 + h * 64);
    float s = 0.f;
#pragma unroll
    for (int i = 0; i < 32; ++i) {
      u32 u = kr[i];
      s += bf2f((u16)(u & 0xFFFF)) * sq[2 * i] + bf2f((u16)(u >> 16)) * sq[2 * i + 1];
    }
    sc[tid] = __expf(s * 0.125f);
  }
  __syncthreads();
  // den partial
  float ds = (tid < nk) ? sc[tid] : 0.f;
  red[tid] = ds;
  __syncthreads();
  for (int st = 128; st > 0; st >>= 1) {
    if (tid < st) red[tid] += red[tid + st];
    __syncthreads();
  }
  // PV partial: thread (kp, dc) accumulates dims [dc,dc+8) over local keys kp+32j
  int kp = tid >> 3, dc = (tid & 7) << 3;
  const u16* vb = kv + (size_t)b * NSEQ * 1536 + DD + h * 64 + dc;
  float acc[8];
#pragma unroll
  for (int i = 0; i < 8; ++i) acc[i] = 0.f;
#pragma unroll
  for (int j = 0; j < 4; ++j) {
    int kl = kp + (j << 5);
    uint4 v = *(const uint4*)(vb + (size_t)(ck * 128 + kl) * 1536);
    float p = sc[kl];
    acc[0] += p * bf2f((u16)(v.x & 0xFFFF));
    acc[1] += p * bf2f((u16)(v.x >> 16));
    acc[2] += p * bf2f((u16)(v.y & 0xFFFF));
    acc[3] += p * bf2f((u16)(v.y >> 16));
    acc[4] += p * bf2f((u16)(v.z & 0xFFFF));
    acc[5] += p * bf2f((u16)(v.z >> 16));
    acc[6] += p * bf2f((u16)(v.w & 0xFFFF));
    acc[7] += p * bf2f((u16)(v.w >> 16));
  }
  if (ck == 7 && kp == 0) {  // key 1024
    uint4 v = *(const uint4*)(vb + (size_t)1024 * 1536);
    float p = sc[128];
    acc[0] += p * bf2f((u16)(v.x & 0xFFFF));
    acc[1] += p * bf2f((u16)(v.x >> 16));
    acc[2] += p * bf2f((u16)(v.y & 0xFFFF));
    acc[3] += p * bf2f((u16)(v.y >> 16));
    acc[4] += p * bf2f((u16)(v.z & 0xFFFF));
    acc[5] += p * bf2f((u16)(v.z >> 16));
    acc[6] += p * bf2f((u16)(v.w & 0xFFFF));
    acc[7] += p * bf2f((u16)(v.w >> 16));
  }
#pragma unroll
  for (int i = 0; i < 8; ++i) rpv[kp][dc + i] = acc[i];
  __syncthreads();
  float* po = part + ((size_t)bh * 8 + ck) * 65;
  if (tid < 64) {
    float s = 0.f;
#pragma unroll
    for (int p = 0; p < 32; ++p) s += rpv[p][tid];
    po[tid] = s;
  }
  if (tid == 64) po[64] = red[0];
}

// ---------------------------------------------------------------------------
// vv_attn (r8 structure, best measured): 32x32x16 MFMA + in-register P via
// permlane32_swap (T12); zero bank conflicts; LDS 16KB; 48.1us floor after
// six structural experiments (conflict-fix -5us; dbuf, 2x-occupancy,
// fence-merge, setprio, DS-byte-cut all null).
// ---------------------------------------------------------------------------
__global__ __launch_bounds__(256, 3) void vv_attn(const u16* __restrict__ vn,
                                                  const u16* __restrict__ vT,
                                                  u16* __restrict__ attn,
                                                  const float* __restrict__ part) {
  __shared__ u16 sK[4096];  // [ds(4)][mt(2)][lane][8]  8KB  (keys x dims, frag order)
  __shared__ u16 sV[4096];  // [ks(4)][nt(2)][lane][8]  8KB  (dims x keys, frag order)

  const int tid = threadIdx.x, w = tid >> 6, lane = tid & 63;
  const int l5 = lane >> 5;
  const int bh = blockIdx.x;        // 0..95
  const int m0 = blockIdx.y << 7;
  const int b = bh / HH, h = bh - b * HH;
  const char* nb = (const char*)(vn + (size_t)bh * KPAD * 64);  // 128B rows (key-major)
  const char* tb = (const char*)(vT + (size_t)bh * 64 * KPAD);  // 2176B rows (d-major)

  // Q B-frags (32x32x16): qreg[ds] = Q[1+m0+w*32+(lane&31)][16ds + l5*8 .. +8)
  short8 qreg[4];
#pragma unroll
  for (int ds = 0; ds < 4; ++ds)
    qreg[ds] = *(const short8*)(nb +
        (size_t)(1 + m0 + (w << 5) + (lane & 31)) * 128 + (ds << 5) + (l5 << 4));

  const char* srcK[2];
  const char* srcV[2];
  int offKV[2];
#pragma unroll
  for (int j = 0; j < 2; ++j) {
    srcK[j] = nb + (size_t)((j << 5) + (lane & 31)) * 128 + (w << 5) + (l5 << 4);
    srcV[j] = tb + (size_t)((j << 5) + (lane & 31)) * (KPAD * 2) + (w << 5) + (l5 << 4);
    offKV[j] = (w << 11) + (j << 10) + (lane << 4);
  }

  f32x16 oacc[2];
  f32x16 dacc;
#pragma unroll
  for (int i = 0; i < 16; ++i) { oacc[0][i] = 0.f; oacc[1][i] = 0.f; dacc[i] = 0.f; }
  short8 ones;
#pragma unroll
  for (int i = 0; i < 8; ++i) ones[i] = (short)0x3F80;  // bf16 1.0

  const float CEXP = 0.1803368801111204f;  // 0.125 * log2(e)

  const char* rdK = (const char*)sK + (lane << 4);
  const char* rdV = (const char*)sV + (lane << 4);

#pragma unroll 1
  for (int kt = 0; kt < 17; ++kt) {
    __syncthreads();  // protect sK/sV from previous iteration's readers
#pragma unroll
    for (int j = 0; j < 2; ++j) {
      gl2lds16(srcK[j] + (size_t)kt * 8192, (char*)sK + offKV[j]);
      gl2lds16(srcV[j] + (size_t)kt * 128,  (char*)sV + offKV[j]);
    }
    __syncthreads();  // vmcnt(0) drain + publish block-wide

    // S^T = Kn_tile @ Qn^T : 2 key-tiles x 4 d-steps
    f32x16 sacc[2];
#pragma unroll
    for (int i = 0; i < 16; ++i) { sacc[0][i] = 0.f; sacc[1][i] = 0.f; }
#pragma unroll
    for (int ds = 0; ds < 4; ++ds) {
      short8 ak0 = *(const short8*)(rdK + ((ds << 1) << 10));
      short8 ak1 = *(const short8*)(rdK + (((ds << 1) + 1) << 10));
      sacc[0] = __builtin_amdgcn_mfma_f32_32x32x16_bf16(ak0, qreg[ds], sacc[0], 0, 0, 0);
      sacc[1] = __builtin_amdgcn_mfma_f32_32x32x16_bf16(ak1, qreg[ds], sacc[1], 0, 0, 0);
    }

    // p = exp2(s*CEXP); pack pairs to bf16; permlane assembles A-frags;
    // PV + den accumulate. All in registers.
#pragma unroll
    for (int mt = 0; mt < 2; ++mt) {
      u32 pk[8];
#pragma unroll
      for (int i = 0; i < 8; ++i) {
        float e0 = __builtin_amdgcn_exp2f(sacc[mt][2 * i] * CEXP);
        float e1 = __builtin_amdgcn_exp2f(sacc[mt][2 * i + 1] * CEXP);
        if (kt == 16) {  // only global key 1024 (mt==0, reg==0, lane<32) valid
          e0 = (mt == 0 && i == 0 && l5 == 0) ? e0 : 0.f;
          e1 = 0.f;
        }
        pk[i] = __builtin_amdgcn_perm(__float_as_uint(e1) + 0x8000u,
                                      __float_as_uint(e0) + 0x8000u, 0x07060302u);
      }
#pragma unroll
      for (int s = 0; s < 2; ++s) {
        u32x2 r0 = pl32swap(pk[4 * s], pk[4 * s + 2]);
        u32x2 r1 = pl32swap(pk[4 * s + 1], pk[4 * s + 3]);
        u32 paw[4] = {r0.x, r1.x, r0.y, r1.y};  // A elems (0,1)(2,3)(4,5)(6,7)
        short8 pa;
#pragma unroll
        for (int q2 = 0; q2 < 4; ++q2) {
          pa[2 * q2]     = (short)(paw[q2] & 0xFFFFu);
          pa[2 * q2 + 1] = (short)(paw[q2] >> 16);
        }
        int ksg = (mt << 1) + s;  // global 16-key step
        short8 bv0 = *(const short8*)(rdV + ((ksg << 1) << 10));
        short8 bv1 = *(const short8*)(rdV + (((ksg << 1) + 1) << 10));
        oacc[0] = __builtin_amdgcn_mfma_f32_32x32x16_bf16(pa, bv0, oacc[0], 0, 0, 0);
        oacc[1] = __builtin_amdgcn_mfma_f32_32x32x16_bf16(pa, bv1, oacc[1], 0, 0, 0);
        dacc    = __builtin_amdgcn_mfma_f32_32x32x16_bf16(pa, ones, dacc, 0, 0, 0);
      }
    }
  }

  // epilogue: lane holds d = 32nt + (lane&31), q = (reg&3)+8*(reg>>2)+4*l5
#pragma unroll
  for (int reg = 0; reg < 16; ++reg) {
    int q = (reg & 3) + ((reg >> 2) << 3) + (l5 << 2);
    int nseq = 1 + m0 + (w << 5) + q;
    float rdn = 1.0f / dacc[reg];
    u16* o = attn + ((size_t)b * NSEQ + nseq) * DD + h * 64 + (lane & 31);
    o[0]  = f2bf(oacc[0][reg] * rdn);
    o[32] = f2bf(oacc[1][reg] * rdn);
  }

  // finalize attention row 0 from row0_part partials (y==0 blocks only)
  if (blockIdx.y == 0 && tid < 64) {
    const float* pp = part + (size_t)bh * 8 * 65;
    float num = 0.f, den = 0.f;
#pragma unroll
    for (int c = 0; c < 8; ++c) {
      num += pp[c * 65 + tid];
      den += pp[c * 65 + 64];
    }
    attn[(size_t)b * NSEQ * DD + h * 64 + tid] = f2bf(num / den);
  }
}

// ---------------------------------------------------------------------------
// launcher
// ---------------------------------------------------------------------------
extern "C" void kernel_launch(void* const* d_in, const int* in_sizes, int n_in,
                              void* d_out, int out_size, void* d_ws, size_t ws_size,
                              hipStream_t stream) {
  const float* x      = (const float*)d_in[0];
  const float* w_qkv  = (const float*)d_in[1];
  const float* w_proj = (const float*)d_in[2];
  const float* b_proj = (const float*)d_in[3];
  float* out = (float*)d_out;
  char* ws = (char*)d_ws;

  // workspace layout (bytes). xb region is reused by vT after the qkv GEMM;
  // wkv region (dead after gemm<0>) is reused by the row-0 partials.
  u16*   xb   = (u16*)(ws + 0);            // 8320*768*2   = 12,779,520
  u16*   vT   = (u16*)(ws + 0);            // 96*64*1088*2 = 13,369,344 (reuses xb)
  u16*   wkv  = (u16*)(ws + 13369344);     // 1536*768*2   =  2,359,296
  float* r0p  = (float*)(ws + 13369344);   // 96*8*65*4    =    199,680 (reuses wkv)
  u16*   wpj  = (u16*)(ws + 15728640);     // 768*768*2    =  1,179,648
  u16*   kvb  = (u16*)(ws + 16908288);     // 8320*1536*2  = 25,559,040
  float* q0   = (float*)(ws + 42467328);   // 8*768*4      =     24,576
  u16*   attn = (u16*)(ws + 42491904);     // 8320*768*2   = 12,779,520
  u16*   vn   = (u16*)(ws + 55271424);     // 96*1088*64*2 = 13,369,344
  // total: 68,640,768 bytes

  prep<<<7968, 256, 0, stream>>>(x, w_qkv, w_proj, xb, wkv, wpj);
  gemm_bt<0, 12><<<864, 256, 0, stream>>>(xb, wkv, kvb, nullptr, nullptr, 1536);
  q0_kernel<<<96, 256, 0, stream>>>(x, w_qkv, q0);
  transpose_v<<<1632, 256, 0, stream>>>(kvb, vT, vn);     // overwrites xb region
  row0_part<<<dim3(96, 8), 256, 0, stream>>>(q0, kvb, r0p);
  vv_attn<<<dim3(96, 8), 256, 0, stream>>>(vn, vT, attn, r0p);
  gemm_proj<<<864, 256, 0, stream>>>(attn, wpj, out, b_proj);
}